// Round 9
// baseline (171.207 us; speedup 1.0000x reference)
//
#include <hip/hip_runtime.h>
#include <hip/hip_bf16.h>

typedef __attribute__((ext_vector_type(8))) short bf16x8;
typedef __attribute__((ext_vector_type(4))) float f32x4;
typedef unsigned short u16;

#define B_  2
#define T_  2048
#define C_  1024
#define H_  16
#define HD_ 64

static __device__ __forceinline__ u16 f2bf(float f) {
  unsigned u = __float_as_uint(f);
  u += 0x7fffu + ((u >> 16) & 1u);   // round-to-nearest-even
  return (u16)(u >> 16);
}
static __device__ __forceinline__ unsigned pk2(float a, float b) {
  __hip_bfloat162 hh = __float22bfloat162_rn(make_float2(a, b));
  return *(unsigned*)&hh;
}

// ---------------------------------------------------------------------------
// Kernel 1 "gemm_fused": qk = bf16(X) @ bf16(W)^T staged straight from fp32
// with register double-buffered prefetch (no Xb/Wb buffers, no prep kernel).
// Side jobs folded in:
//   - at k-iteration it == blockIdx.x, the As tile is X[b, tloc..+128,
//     h=it*64..+64] -> emit Vf fragment tiles (2 kt units) + SubP64 col sums.
//   - Q written PRE-SCALED 0.125 in MFMA-A-fragment-linear layout Qf.
//   - K written in MFMA-B-fragment-linear layout Kf.
// ---------------------------------------------------------------------------
__device__ __forceinline__ void mfma_step(
    const u16* As, const u16* Bs, f32x4 (&acc)[4][4],
    int wr, int wc, int quad, int l16)
{
#pragma unroll
  for (int c = 0; c < 2; ++c) {
    bf16x8 af[4], bf[4];
#pragma unroll
    for (int i = 0; i < 4; ++i)
      af[i] = *(const bf16x8*)&As[(wr + i * 16 + l16) * 64 + c * 32 + quad * 8];
#pragma unroll
    for (int j = 0; j < 4; ++j)
      bf[j] = *(const bf16x8*)&Bs[(wc + j * 16 + l16) * 64 + c * 32 + quad * 8];
#pragma unroll
    for (int i = 0; i < 4; ++i)
#pragma unroll
      for (int j = 0; j < 4; ++j)
        acc[i][j] = __builtin_amdgcn_mfma_f32_16x16x32_bf16(af[i], bf[j], acc[i][j], 0, 0, 0);
  }
}

__device__ __forceinline__ void emit_vf(
    const u16* As, u16* __restrict__ Vf, float* __restrict__ SubP64,
    int bh, int kt0, int w, int lane, int quad, int l16)
{
#pragma unroll
  for (int kk = 0; kk < 2; ++kk) {
    u16* outb = Vf + ((size_t)bh * 32 + kt0 + kk) * 4096;
    float cs = 0.f;
#pragma unroll
    for (int c = 0; c < 2; ++c) {
      u16 tmp[8];
#pragma unroll
      for (int j = 0; j < 8; ++j) {
        u16 v = As[(kk * 64 + c * 32 + quad * 8 + j) * 64 + w * 16 + l16];
        tmp[j] = v;
        cs += __uint_as_float(((unsigned)v) << 16);
      }
      *(bf16x8*)&outb[((w * 2 + c) * 64 + lane) * 8] = *(const bf16x8*)tmp;
    }
    cs += __shfl_xor(cs, 16);
    cs += __shfl_xor(cs, 32);
    if (quad == 0)
      SubP64[(size_t)bh * 2048 + (kt0 + kk) * 64 + w * 16 + l16] = cs;
  }
}

__global__ __launch_bounds__(256, 2) void gemm_fused(
    const float* __restrict__ X, const float* __restrict__ W,
    u16* __restrict__ Qf, u16* __restrict__ Kf,
    u16* __restrict__ Vf, float* __restrict__ SubP64)
{
  __shared__ __align__(16) u16 As[128 * 64];
  __shared__ __align__(16) u16 Bs[128 * 64];

  const int tid  = threadIdx.x;
  const int w    = tid >> 6;
  const int lane = tid & 63;
  const int quad = lane >> 4;
  const int l16  = lane & 15;
  const int m0 = blockIdx.y * 128;
  const int n0 = blockIdx.x * 128;
  const int srow = tid >> 3;             // staging row 0..31 (+s*32)
  const int scol = (tid & 7) * 8;        // staging col (elements)

  const float* Xs = X + (size_t)(m0 + srow) * C_ + scol;
  const float* Ws = W + (size_t)(n0 + srow) * C_ + scol;

  f32x4 zero = {0.f, 0.f, 0.f, 0.f};
  f32x4 acc[4][4];
#pragma unroll
  for (int i = 0; i < 4; ++i)
#pragma unroll
    for (int j = 0; j < 4; ++j) acc[i][j] = zero;

  const int wr = (w >> 1) * 64, wc = (w & 1) * 64;
  const int bidx = (int)blockIdx.y >> 4;
  const int tloc0 = m0 & 2047;

#define ISSUE(K, BA, BB)                                              \
  {                                                                   \
    _Pragma("unroll") for (int s = 0; s < 4; ++s) {                   \
      const float* gx = Xs + (size_t)s * 32 * C_ + (K);               \
      BA[s * 2]     = *(const float4*)gx;                             \
      BA[s * 2 + 1] = *(const float4*)(gx + 4);                       \
      const float* gw = Ws + (size_t)s * 32 * C_ + (K);               \
      BB[s * 2]     = *(const float4*)gw;                             \
      BB[s * 2 + 1] = *(const float4*)(gw + 4);                       \
    }                                                                 \
  }
#define COMMIT(BA, BB)                                                \
  {                                                                   \
    _Pragma("unroll") for (int s = 0; s < 4; ++s) {                   \
      union { unsigned u[4]; bf16x8 v; } pa, pb;                      \
      pa.u[0] = pk2(BA[s * 2].x, BA[s * 2].y);                        \
      pa.u[1] = pk2(BA[s * 2].z, BA[s * 2].w);                        \
      pa.u[2] = pk2(BA[s * 2 + 1].x, BA[s * 2 + 1].y);                \
      pa.u[3] = pk2(BA[s * 2 + 1].z, BA[s * 2 + 1].w);                \
      pb.u[0] = pk2(BB[s * 2].x, BB[s * 2].y);                        \
      pb.u[1] = pk2(BB[s * 2].z, BB[s * 2].w);                        \
      pb.u[2] = pk2(BB[s * 2 + 1].x, BB[s * 2 + 1].y);                \
      pb.u[3] = pk2(BB[s * 2 + 1].z, BB[s * 2 + 1].w);                \
      *(bf16x8*)&As[(s * 32 + srow) * 64 + scol] = pa.v;              \
      *(bf16x8*)&Bs[(s * 32 + srow) * 64 + scol] = pb.v;              \
    }                                                                 \
  }

  float4 a0[8], b0[8], a1[8], b1[8];
  ISSUE(0, a0, b0);
  for (int it = 0; it < 16; it += 2) {
    ISSUE((it + 1) * 64, a1, b1);
    COMMIT(a0, b0);
    __syncthreads();
    mfma_step(As, Bs, acc, wr, wc, quad, l16);
    if (it == (int)blockIdx.x)
      emit_vf(As, Vf, SubP64, bidx * H_ + blockIdx.x, tloc0 >> 6, w, lane, quad, l16);
    __syncthreads();
    if (it + 2 < 16) ISSUE((it + 2) * 64, a0, b0);
    COMMIT(a1, b1);
    __syncthreads();
    mfma_step(As, Bs, acc, wr, wc, quad, l16);
    if (it + 1 == (int)blockIdx.x)
      emit_vf(As, Vf, SubP64, bidx * H_ + blockIdx.x, tloc0 >> 6, w, lane, quad, l16);
    __syncthreads();
  }
#undef ISSUE
#undef COMMIT

  // epilogue scatter. C/D layout: col=lane&15, row=quad*4+reg (m89/m91).
#pragma unroll
  for (int i = 0; i < 4; ++i) {
    const int tloc = tloc0 + wr + i * 16;      // 16-aligned row base in T
#pragma unroll
    for (int j = 0; j < 4; ++j) {
      const int n = n0 + wc + j * 16 + l16;    // wave-uniform branch base
      if (n < C_) {
        const int hq = n >> 6;                 // wave-uniform
        const int d = n & 63;
        u16* qp = Qf + ((size_t)(bidx * H_ + hq) * 128 + (tloc >> 4)) * 1024
                  + ((size_t)((d >> 5) * 64 + ((d >> 3) & 3) * 16 + quad * 4)) * 8
                  + (d & 7);
#pragma unroll
        for (int r = 0; r < 4; ++r) qp[(size_t)r * 8] = f2bf(0.125f * acc[i][j][r]);
      } else {
        const int nh = n - C_;
        const int hh = nh >> 6, d = nh & 63;
        u16* kp = Kf + (((((size_t)(bidx * H_ + hh) * 32 + (tloc >> 6)) * 4
                          + ((tloc >> 4) & 3)) * 2 + (d >> 5)) * 64
                        + ((d >> 3) & 3) * 16 + quad * 4) * 8 + (d & 7);
#pragma unroll
        for (int r = 0; r < 4; ++r) kp[(size_t)r * 8] = f2bf(acc[i][j][r]);
      }
    }
  }
}

// ---------------------------------------------------------------------------
// Kernel 2: software-pipelined barrier-free flash attention + fused epilogue
// (round-6/8 structure; Q/K/V all fragment-linear coalesced loads).
// ---------------------------------------------------------------------------
__device__ __forceinline__ void load_kv(
    bf16x8 (&kf)[2][4], bf16x8 (&vf)[2][4],
    const u16* __restrict__ kbase, const u16* __restrict__ vbase, int lane)
{
#pragma unroll
  for (int c = 0; c < 2; ++c)
#pragma unroll
    for (int nb = 0; nb < 4; ++nb) {
      kf[c][nb] = *(const bf16x8*)&kbase[((nb * 2 + c) * 64 + lane) * 8];
      vf[c][nb] = *(const bf16x8*)&vbase[((nb * 2 + c) * 64 + lane) * 8];
    }
}

__device__ __forceinline__ void tile_compute(
    const bf16x8 (&qfrag)[2], const bf16x8 (&kf)[2][4], const bf16x8 (&vf)[2][4],
    f32x4 (&acc)[4], f32x4& accl, float (*pb)[68],
    int quad, int l16, int myrow, bool diag, bf16x8 onesf)
{
  f32x4 zero = {0.f, 0.f, 0.f, 0.f};
  f32x4 sfr[4] = {zero, zero, zero, zero};
#pragma unroll
  for (int cc = 0; cc < 2; ++cc)
#pragma unroll
    for (int nb = 0; nb < 4; ++nb)
      sfr[nb] = __builtin_amdgcn_mfma_f32_16x16x32_bf16(qfrag[cc], kf[cc][nb], sfr[nb], 0, 0, 0);

#pragma unroll
  for (int nb = 0; nb < 4; ++nb)
#pragma unroll
    for (int r = 0; r < 4; ++r) {
      float p = __expf(sfr[nb][r]);
      if (diag && (nb * 16 + l16 > myrow + r)) p = 0.f;
      pb[quad * 4 + r][nb * 16 + l16] = p;
    }

#pragma unroll
  for (int cc = 0; cc < 2; ++cc) {
    f32x4 plo = *(const f32x4*)&pb[l16][cc * 32 + quad * 8];
    f32x4 phi = *(const f32x4*)&pb[l16][cc * 32 + quad * 8 + 4];
    union { unsigned u[4]; bf16x8 v; } pk;
    pk.u[0] = pk2(plo[0], plo[1]);
    pk.u[1] = pk2(plo[2], plo[3]);
    pk.u[2] = pk2(phi[0], phi[1]);
    pk.u[3] = pk2(phi[2], phi[3]);
    accl = __builtin_amdgcn_mfma_f32_16x16x32_bf16(pk.v, onesf, accl, 0, 0, 0);
#pragma unroll
    for (int nb = 0; nb < 4; ++nb)
      acc[nb] = __builtin_amdgcn_mfma_f32_16x16x32_bf16(pk.v, vf[cc][nb], acc[nb], 0, 0, 0);
  }
}

__global__ __launch_bounds__(256) void attn_kernel(
    const u16* __restrict__ Qf, const u16* __restrict__ Kf, const u16* __restrict__ Vf,
    const float* __restrict__ SubP64, const float* __restrict__ X, float* __restrict__ out,
    const float* __restrict__ alphap, const float* __restrict__ betap,
    const float* __restrict__ gammap)
{
  // main phase: pbufF[4][16][68] f32 (17408 B); epilogue aliases:
  // Xt[64][68] (17408 B) + G[4][64] + GP[4][64] (2048 B)
  __shared__ __align__(16) char smem[19456];

  const int tid  = threadIdx.x;
  const int w    = tid >> 6;
  const int lane = tid & 63;
  const int quad = lane >> 4;
  const int l16  = lane & 15;
  const int qt = 31 - blockIdx.y;        // LPT
  const int bh = blockIdx.x;
  const int b = bh >> 4, h = bh & 15;

  const u16* kfb = Kf + (size_t)bh * T_ * HD_;
  const u16* vfb = Vf + (size_t)bh * T_ * HD_;

  bf16x8 qfrag[2];
  {
    const u16* qp = Qf + ((size_t)bh * 128 + qt * 4 + w) * 1024;
    qfrag[0] = *(const bf16x8*)&qp[lane * 8];
    qfrag[1] = *(const bf16x8*)&qp[(64 + lane) * 8];
  }

  bf16x8 onesf;
#pragma unroll
  for (int j = 0; j < 8; ++j) onesf[j] = (short)0x3F80;

  f32x4 zero = {0.f, 0.f, 0.f, 0.f};
  f32x4 acc[4] = {zero, zero, zero, zero};
  f32x4 accl = zero;
  const int myrow = w * 16 + quad * 4;
  float (*pb)[68] = (float(*)[68])((float*)smem + (size_t)w * 16 * 68);

  bf16x8 kA[2][4], vA[2][4], kB[2][4], vB[2][4];
  load_kv(kA, vA, kfb, vfb, lane);
  int kt = 0;
  for (;;) {
    int ktn = (kt + 1 < qt) ? kt + 1 : qt;
    load_kv(kB, vB, kfb + (size_t)ktn * 4096, vfb + (size_t)ktn * 4096, lane);
    tile_compute(qfrag, kA, vA, acc, accl, pb, quad, l16, myrow, kt == qt, onesf);
    if (kt + 1 > qt) break;
    int ktn2 = (kt + 2 < qt) ? kt + 2 : qt;
    load_kv(kA, vA, kfb + (size_t)ktn2 * 4096, vfb + (size_t)ktn2 * 4096, lane);
    tile_compute(qfrag, kB, vB, acc, accl, pb, quad, l16, myrow, kt + 1 == qt, onesf);
    kt += 2;
    if (kt > qt) break;
  }

  // ---------------- fused epilogue ----------------
  __syncthreads();                        // all waves done with pbufF
  float* Xt = (float*)smem;               // [64][68]
  float* G  = (float*)(smem + 17408);     // [4][64]
  float* GP = (float*)(smem + 18432);     // [4][64]

  {
    const int row = tid >> 2, c0 = (tid & 3) * 16;
    const float* xp = X + ((size_t)b * T_ + qt * 64 + row) * C_ + h * 64 + c0;
#pragma unroll
    for (int q = 0; q < 4; ++q) {
      float4 v = *(const float4*)(xp + q * 4);
      Xt[row * 68 + c0 + q * 4 + 0] = v.x;
      Xt[row * 68 + c0 + q * 4 + 1] = v.y;
      Xt[row * 68 + c0 + q * 4 + 2] = v.z;
      Xt[row * 68 + c0 + q * 4 + 3] = v.w;
    }
  }
  {
    float p = 0.f;
    for (int i = w; i < qt; i += 4)
      p += SubP64[(size_t)bh * 2048 + i * 64 + lane];
    GP[w * 64 + lane] = p;
  }
  __syncthreads();
  {
    float g = 0.f;
#pragma unroll
    for (int i = 0; i < 16; ++i) g += Xt[(w * 16 + i) * 68 + lane];
    G[w * 64 + lane] = g;
  }
  __syncthreads();
  {
    const float alpha = *alphap, gamma = *gammap;
    float run = GP[lane] + GP[64 + lane] + GP[128 + lane] + GP[192 + lane];
    for (int g = 0; g < w; ++g) run += G[g * 64 + lane];
    const int tbase = qt * 64 + w * 16;
#pragma unroll
    for (int i = 0; i < 16; ++i) {
      float v = Xt[(w * 16 + i) * 68 + lane];
      run += v;
      Xt[(w * 16 + i) * 68 + lane] =
          alpha * v - gamma * run * __builtin_amdgcn_rcpf((float)(tbase + i + 1));
    }
  }
  __syncthreads();

  const float beta = *betap;
  float rl[4];
#pragma unroll
  for (int r = 0; r < 4; ++r) rl[r] = beta * __builtin_amdgcn_rcpf(accl[r]);
#pragma unroll
  for (int nb = 0; nb < 4; ++nb) {
#pragma unroll
    for (int r = 0; r < 4; ++r) {
      int t = qt * 64 + myrow + r;
      int d = nb * 16 + l16;
      out[((size_t)b * T_ + t) * C_ + h * 64 + d] =
          Xt[(myrow + r) * 68 + d] + rl[r] * acc[nb][r];
    }
  }
}

// ---------------------------------------------------------------------------
extern "C" void kernel_launch(void* const* d_in, const int* in_sizes, int n_in,
                              void* d_out, int out_size, void* d_ws, size_t ws_size,
                              hipStream_t stream) {
  const float* x      = (const float*)d_in[0];
  const float* W_attn = (const float*)d_in[1];
  const float* alphap = (const float*)d_in[2];
  const float* betap  = (const float*)d_in[3];
  const float* gammap = (const float*)d_in[4];
  float* out = (float*)d_out;

  // ws: Qf@0(8M) Kf@8(8M) Vf@16(8M) SubP64@24(.25M) = 24.25M
  char* ws = (char*)d_ws;
  u16*   Qfb    = (u16*)(ws);
  u16*   Kfb    = (u16*)(ws + (8ull  << 20));
  u16*   Vfb    = (u16*)(ws + (16ull << 20));
  float* SubP64 = (float*)(ws + (24ull << 20));

  gemm_fused<<<dim3(16, 32), 256, 0, stream>>>(x, W_attn, Qfb, Kfb, Vfb, SubP64);
  attn_kernel<<<dim3(32, 32), 256, 0, stream>>>(Qfb, Kfb, Vfb, SubP64, x, out,
                                                alphap, betap, gammap);
}

// Round 10
// 151.626 us; speedup vs baseline: 1.1291x; 1.1291x over previous
//
#include <hip/hip_runtime.h>
#include <hip/hip_bf16.h>

typedef __attribute__((ext_vector_type(8))) short bf16x8;
typedef __attribute__((ext_vector_type(4))) float f32x4;
typedef unsigned short u16;

#define B_  2
#define T_  2048
#define C_  1024
#define H_  16
#define HD_ 64

static __device__ __forceinline__ u16 f2bf(float f) {
  unsigned u = __float_as_uint(f);
  u += 0x7fffu + ((u >> 16) & 1u);   // round-to-nearest-even
  return (u16)(u >> 16);
}

// ---------------------------------------------------------------------------
// Kernel 0 "prep": two regions in one dispatch
//   [0,1024):   pack block (bh,kt): read 64x64 X tile fp32 once ->
//               Xb (bf16 row-major), Vf (MFMA-fragment layout), and
//               SubP64[bh][kt][d] = column sums (fp32, via xor-shuffles)
//   [1024,3072): convert W fp32->bf16 (float4 vectorized)
// ---------------------------------------------------------------------------
#define NW4 524288    // W float4 count
__global__ __launch_bounds__(256) void prep(
    const float* __restrict__ X, const float* __restrict__ W,
    u16* __restrict__ Xb, u16* __restrict__ Wb,
    u16* __restrict__ Vf, float* __restrict__ SubP64)
{
  __shared__ u16 tr[64][65];
  __shared__ float cs[4][64];
  const int blk = blockIdx.x;
  const int tid = threadIdx.x;

  if (blk < 1024) {                       // ---- pack + convert-X + colsums ----
    const int kt = blk & 31, bh = blk >> 5;
    const int b = bh >> 4, h = bh & 15;
    const int w = tid >> 6, lane = tid & 63;
    {
      const int row = tid >> 2;            // 0..63
      const int c0  = (tid & 3) * 16;      // float col base
      const float* xp = X + ((size_t)b * T_ + kt * 64 + row) * C_ + h * 64 + c0;
      float vals[16];
#pragma unroll
      for (int q = 0; q < 4; ++q) {
        float4 v = *(const float4*)(xp + q * 4);
        vals[q * 4 + 0] = v.x; vals[q * 4 + 1] = v.y;
        vals[q * 4 + 2] = v.z; vals[q * 4 + 3] = v.w;
      }
      u16 xb[16];
#pragma unroll
      for (int i = 0; i < 16; ++i) xb[i] = f2bf(vals[i]);
      u16* xq = Xb + ((size_t)(b * T_ + kt * 64 + row)) * C_ + h * 64 + c0;
      *(bf16x8*)xq       = *(const bf16x8*)&xb[0];
      *(bf16x8*)(xq + 8) = *(const bf16x8*)&xb[8];
#pragma unroll
      for (int i = 0; i < 16; ++i) tr[row][c0 + i] = xb[i];
#pragma unroll
      for (int m = 4; m <= 32; m <<= 1)
#pragma unroll
        for (int i = 0; i < 16; ++i) vals[i] += __shfl_xor(vals[i], m);
      if (lane < 4) {
        float* dst = &cs[w][lane * 16];
#pragma unroll
        for (int q = 0; q < 4; ++q) {
          f32x4 s4 = { vals[q * 4 + 0], vals[q * 4 + 1], vals[q * 4 + 2], vals[q * 4 + 3] };
          *(f32x4*)&dst[q * 4] = s4;
        }
      }
    }
    __syncthreads();
    {
      const int quad = (lane >> 4), l16 = lane & 15;
      u16* outb = Vf + ((size_t)bh * 32 + kt) * 4096;
#pragma unroll
      for (int c = 0; c < 2; ++c) {
        u16 tmp[8];
#pragma unroll
        for (int j = 0; j < 8; ++j) tmp[j] = tr[c * 32 + quad * 8 + j][w * 16 + l16];
        *(bf16x8*)&outb[((w * 2 + c) * 64 + lane) * 8] = *(const bf16x8*)tmp;
      }
    }
    if (tid < 64)
      SubP64[(size_t)bh * 2048 + kt * 64 + tid] =
          cs[0][tid] + cs[1][tid] + cs[2][tid] + cs[3][tid];
  } else {                                // ---- convert W ----
    int i = (blk - 1024) * 256 + tid;
    float4 v = ((const float4*)W)[i];
    ushort4 u = { f2bf(v.x), f2bf(v.y), f2bf(v.z), f2bf(v.w) };
    ((ushort4*)Wb)[i] = u;
  }
}

// ---------------------------------------------------------------------------
// Kernel 1: qk = Xb @ Wb^T  (M=4096,N=2048,K=1024), 128x128 tile, BK=64,
// global_load_lds width=16, LDS DOUBLE-BUFFERED: one barrier per K-iter,
// next tile's async loads fly during current tile's MFMA.
// Q row-major [B,H,T,hd] PRE-SCALED by 0.125; K into fragment-linear Kf.
// ---------------------------------------------------------------------------
__global__ __launch_bounds__(256) void gemm_qk(
    const u16* __restrict__ Xb, const u16* __restrict__ Wb,
    u16* __restrict__ Qo, u16* __restrict__ Kf)
{
  __shared__ __align__(16) u16 As[2][128 * 64];
  __shared__ __align__(16) u16 Bs[2][128 * 64];

  const int tid  = threadIdx.x;
  const int w    = tid >> 6;
  const int lane = tid & 63;
  const int quad = lane >> 4;
  const int l16  = lane & 15;
  const int m0 = blockIdx.y * 128;
  const int n0 = blockIdx.x * 128;

  const int grow = w * 8 + ((lane >> 3) & 7);
  const int gcol = (lane & 7) * 8;

  f32x4 zero = {0.f, 0.f, 0.f, 0.f};
  f32x4 acc[4][4];
#pragma unroll
  for (int i = 0; i < 4; ++i)
#pragma unroll
    for (int j = 0; j < 4; ++j) acc[i][j] = zero;

  const int wr = (w >> 1) * 64, wc = (w & 1) * 64;

  const u16* gax = Xb + (size_t)(m0 + grow) * C_ + gcol;
  const u16* gbx = Wb + (size_t)(n0 + grow) * C_ + gcol;

#define GISSUE(K, BUF)                                                      \
  {                                                                         \
    _Pragma("unroll") for (int r = 0; r < 4; ++r) {                         \
      __builtin_amdgcn_global_load_lds(                                     \
          (const __attribute__((address_space(1))) void*)(gax + (size_t)r * 32 * C_ + (K)), \
          (__attribute__((address_space(3))) void*)&As[BUF][(w * 8 + r * 32) * 64], \
          16, 0, 0);                                                        \
      __builtin_amdgcn_global_load_lds(                                     \
          (const __attribute__((address_space(1))) void*)(gbx + (size_t)r * 32 * C_ + (K)), \
          (__attribute__((address_space(3))) void*)&Bs[BUF][(w * 8 + r * 32) * 64], \
          16, 0, 0);                                                        \
    }                                                                       \
  }

  GISSUE(0, 0);
#pragma unroll 2
  for (int it = 0; it < 16; ++it) {
    const int cur = it & 1;
    __syncthreads();                 // publishes buf[cur]; buf[cur^1] free
    if (it < 15) GISSUE((it + 1) * 64, cur ^ 1);
#pragma unroll
    for (int c = 0; c < 2; ++c) {
      bf16x8 af[4], bf[4];
#pragma unroll
      for (int i = 0; i < 4; ++i)
        af[i] = *(const bf16x8*)&As[cur][(wr + i * 16 + l16) * 64 + c * 32 + quad * 8];
#pragma unroll
      for (int j = 0; j < 4; ++j)
        bf[j] = *(const bf16x8*)&Bs[cur][(wc + j * 16 + l16) * 64 + c * 32 + quad * 8];
#pragma unroll
      for (int i = 0; i < 4; ++i)
#pragma unroll
        for (int j = 0; j < 4; ++j)
          acc[i][j] = __builtin_amdgcn_mfma_f32_16x16x32_bf16(af[i], bf[j], acc[i][j], 0, 0, 0);
    }
  }
#undef GISSUE

  // C/D layout: col = lane&15, row = quad*4 + reg (verified m89/m91)
#pragma unroll
  for (int i = 0; i < 4; ++i) {
    const int t_base = m0 + wr + i * 16;       // 16-aligned
    const int bidx = t_base >> 11;
    const int kt   = (t_base & 2047) >> 6;
    const int trow = (t_base & 2047) + quad * 4;
#pragma unroll
    for (int j = 0; j < 4; ++j) {
      const int n = n0 + wc + j * 16 + l16;    // wave-uniform branch base
      if (n < C_) {
        const int hq = n >> 6, d = n & 63;
        u16* qp = Qo + (((size_t)bidx * H_ + hq) * T_ + trow) * HD_ + d;
#pragma unroll
        for (int r = 0; r < 4; ++r) qp[(size_t)r * HD_] = f2bf(0.125f * acc[i][j][r]);
      } else {
        const int nh = n - C_;
        const int hh = nh >> 6, d = nh & 63;
        u16* kp = Kf + (((((size_t)(bidx * H_ + hh) * 32 + kt) * 4 + i) * 2 + (d >> 5)) * 64
                        + ((d >> 3) & 3) * 16 + quad * 4) * 8 + (d & 7);
#pragma unroll
        for (int r = 0; r < 4; ++r) kp[(size_t)r * 8] = f2bf(acc[i][j][r]);
      }
    }
  }
}

// ---------------------------------------------------------------------------
// Kernel 2: software-pipelined barrier-free flash attention + fused epilogue
// (round-8 structure, unchanged).
// ---------------------------------------------------------------------------
__device__ __forceinline__ void load_kv(
    bf16x8 (&kf)[2][4], bf16x8 (&vf)[2][4],
    const u16* __restrict__ kbase, const u16* __restrict__ vbase, int lane)
{
#pragma unroll
  for (int c = 0; c < 2; ++c)
#pragma unroll
    for (int nb = 0; nb < 4; ++nb) {
      kf[c][nb] = *(const bf16x8*)&kbase[((nb * 2 + c) * 64 + lane) * 8];
      vf[c][nb] = *(const bf16x8*)&vbase[((nb * 2 + c) * 64 + lane) * 8];
    }
}

__device__ __forceinline__ void tile_compute(
    const bf16x8 (&qfrag)[2], const bf16x8 (&kf)[2][4], const bf16x8 (&vf)[2][4],
    f32x4 (&acc)[4], f32x4& accl, float (*pb)[68],
    int quad, int l16, int myrow, bool diag, bf16x8 onesf)
{
  f32x4 zero = {0.f, 0.f, 0.f, 0.f};
  f32x4 sfr[4] = {zero, zero, zero, zero};
#pragma unroll
  for (int cc = 0; cc < 2; ++cc)
#pragma unroll
    for (int nb = 0; nb < 4; ++nb)
      sfr[nb] = __builtin_amdgcn_mfma_f32_16x16x32_bf16(qfrag[cc], kf[cc][nb], sfr[nb], 0, 0, 0);

#pragma unroll
  for (int nb = 0; nb < 4; ++nb)
#pragma unroll
    for (int r = 0; r < 4; ++r) {
      float p = __expf(sfr[nb][r]);
      if (diag && (nb * 16 + l16 > myrow + r)) p = 0.f;
      pb[quad * 4 + r][nb * 16 + l16] = p;
    }

#pragma unroll
  for (int cc = 0; cc < 2; ++cc) {
    f32x4 plo = *(const f32x4*)&pb[l16][cc * 32 + quad * 8];
    f32x4 phi = *(const f32x4*)&pb[l16][cc * 32 + quad * 8 + 4];
    union { unsigned u[4]; bf16x8 v; } pk;
    __hip_bfloat162 hh;
    hh = __float22bfloat162_rn(make_float2(plo[0], plo[1])); pk.u[0] = *(unsigned*)&hh;
    hh = __float22bfloat162_rn(make_float2(plo[2], plo[3])); pk.u[1] = *(unsigned*)&hh;
    hh = __float22bfloat162_rn(make_float2(phi[0], phi[1])); pk.u[2] = *(unsigned*)&hh;
    hh = __float22bfloat162_rn(make_float2(phi[2], phi[3])); pk.u[3] = *(unsigned*)&hh;
    accl = __builtin_amdgcn_mfma_f32_16x16x32_bf16(pk.v, onesf, accl, 0, 0, 0);
#pragma unroll
    for (int nb = 0; nb < 4; ++nb)
      acc[nb] = __builtin_amdgcn_mfma_f32_16x16x32_bf16(pk.v, vf[cc][nb], acc[nb], 0, 0, 0);
  }
}

__global__ __launch_bounds__(256) void attn_kernel(
    const u16* __restrict__ Q, const u16* __restrict__ Kf, const u16* __restrict__ Vf,
    const float* __restrict__ SubP64, const float* __restrict__ X, float* __restrict__ out,
    const float* __restrict__ alphap, const float* __restrict__ betap,
    const float* __restrict__ gammap)
{
  __shared__ __align__(16) char smem[19456];

  const int tid  = threadIdx.x;
  const int w    = tid >> 6;
  const int lane = tid & 63;
  const int quad = lane >> 4;
  const int l16  = lane & 15;
  const int qt = 31 - blockIdx.y;        // LPT
  const int bh = blockIdx.x;
  const int b = bh >> 4, h = bh & 15;

  const u16* kfb = Kf + (size_t)bh * T_ * HD_;
  const u16* vfb = Vf + (size_t)bh * T_ * HD_;

  bf16x8 qfrag[2];
  {
    const u16* qp = Q + ((size_t)bh * T_ + qt * 64 + w * 16 + l16) * HD_ + quad * 8;
    qfrag[0] = *(const bf16x8*)qp;
    qfrag[1] = *(const bf16x8*)(qp + 32);
  }

  bf16x8 onesf;
#pragma unroll
  for (int j = 0; j < 8; ++j) onesf[j] = (short)0x3F80;

  f32x4 zero = {0.f, 0.f, 0.f, 0.f};
  f32x4 acc[4] = {zero, zero, zero, zero};
  f32x4 accl = zero;
  const int myrow = w * 16 + quad * 4;
  float (*pb)[68] = (float(*)[68])((float*)smem + (size_t)w * 16 * 68);

  bf16x8 kA[2][4], vA[2][4], kB[2][4], vB[2][4];
  load_kv(kA, vA, kfb, vfb, lane);
  int kt = 0;
  for (;;) {
    int ktn = (kt + 1 < qt) ? kt + 1 : qt;
    load_kv(kB, vB, kfb + (size_t)ktn * 4096, vfb + (size_t)ktn * 4096, lane);
    tile_compute(qfrag, kA, vA, acc, accl, pb, quad, l16, myrow, kt == qt, onesf);
    if (kt + 1 > qt) break;
    int ktn2 = (kt + 2 < qt) ? kt + 2 : qt;
    load_kv(kA, vA, kfb + (size_t)ktn2 * 4096, vfb + (size_t)ktn2 * 4096, lane);
    tile_compute(qfrag, kB, vB, acc, accl, pb, quad, l16, myrow, kt + 1 == qt, onesf);
    kt += 2;
    if (kt > qt) break;
  }

  // ---------------- fused epilogue ----------------
  __syncthreads();                        // all waves done with pbufF
  float* Xt = (float*)smem;               // [64][68]
  float* G  = (float*)(smem + 17408);     // [4][64]
  float* GP = (float*)(smem + 18432);     // [4][64]

  {
    const int row = tid >> 2, c0 = (tid & 3) * 16;
    const float* xp = X + ((size_t)b * T_ + qt * 64 + row) * C_ + h * 64 + c0;
#pragma unroll
    for (int q = 0; q < 4; ++q) {
      float4 v = *(const float4*)(xp + q * 4);
      Xt[row * 68 + c0 + q * 4 + 0] = v.x;
      Xt[row * 68 + c0 + q * 4 + 1] = v.y;
      Xt[row * 68 + c0 + q * 4 + 2] = v.z;
      Xt[row * 68 + c0 + q * 4 + 3] = v.w;
    }
  }
  {
    float p = 0.f;
    for (int i = w; i < qt; i += 4)
      p += SubP64[(size_t)bh * 2048 + i * 64 + lane];
    GP[w * 64 + lane] = p;
  }
  __syncthreads();
  {
    float g = 0.f;
#pragma unroll
    for (int i = 0; i < 16; ++i) g += Xt[(w * 16 + i) * 68 + lane];
    G[w * 64 + lane] = g;
  }
  __syncthreads();
  {
    const float alpha = *alphap, gamma = *gammap;
    float run = GP[lane] + GP[64 + lane] + GP[128 + lane] + GP[192 + lane];
    for (int g = 0; g < w; ++g) run += G[g * 64 + lane];
    const int tbase = qt * 64 + w * 16;
#pragma unroll
    for (int i = 0; i < 16; ++i) {
      float v = Xt[(w * 16 + i) * 68 + lane];
      run += v;
      Xt[(w * 16 + i) * 68 + lane] =
          alpha * v - gamma * run * __builtin_amdgcn_rcpf((float)(tbase + i + 1));
    }
  }
  __syncthreads();

  const float beta = *betap;
  float rl[4];
#pragma unroll
  for (int r = 0; r < 4; ++r) rl[r] = beta * __builtin_amdgcn_rcpf(accl[r]);
#pragma unroll
  for (int nb = 0; nb < 4; ++nb) {
#pragma unroll
    for (int r = 0; r < 4; ++r) {
      int t = qt * 64 + myrow + r;
      int d = nb * 16 + l16;
      out[((size_t)b * T_ + t) * C_ + h * 64 + d] =
          Xt[(myrow + r) * 68 + d] + rl[r] * acc[nb][r];
    }
  }
}

// ---------------------------------------------------------------------------
extern "C" void kernel_launch(void* const* d_in, const int* in_sizes, int n_in,
                              void* d_out, int out_size, void* d_ws, size_t ws_size,
                              hipStream_t stream) {
  const float* x      = (const float*)d_in[0];
  const float* W_attn = (const float*)d_in[1];
  const float* alphap = (const float*)d_in[2];
  const float* betap  = (const float*)d_in[3];
  const float* gammap = (const float*)d_in[4];
  float* out = (float*)d_out;

  // ws: Qb@0(8M) Kf@8(8M) Vf@16(8M) SubP64@24(.25M) Xb@25(8M) Wb@33(4M) = 37M
  char* ws = (char*)d_ws;
  u16*   Qb     = (u16*)(ws);
  u16*   Kfb    = (u16*)(ws + (8ull  << 20));
  u16*   Vfb    = (u16*)(ws + (16ull << 20));
  float* SubP64 = (float*)(ws + (24ull << 20));
  u16*   Xb     = (u16*)(ws + (25ull << 20));
  u16*   Wb     = (u16*)(ws + (33ull << 20));

  prep<<<3072, 256, 0, stream>>>(x, W_attn, Xb, Wb, Vfb, SubP64);
  gemm_qk<<<dim3(16, 32), 256, 0, stream>>>(Xb, Wb, Qb, Kfb);
  attn_kernel<<<dim3(32, 32), 256, 0, stream>>>(Qb, Kfb, Vfb, SubP64, x, out,
                                                alphap, betap, gammap);
}